// Round 13
// baseline (497.805 us; speedup 1.0000x reference)
//
#include <hip/hip_runtime.h>

#define BB 8
#define VV 1200
#define DD 64
#define KH 2     // hops
#define NH 4     // heads
#define CAP 64        // hop1 cap
#define NB2CAP 384    // hop2 cap
#define NROW (BB*VV)          // 9600
#define NKROW (KH*BB*VV)      // 19200

__device__ __forceinline__ float wredsum(float v) {
#pragma unroll
  for (int o = 32; o > 0; o >>= 1) v += __shfl_xor(v, o, 64);
  return v;
}
// reduce across 32-lane groups
__device__ __forceinline__ float gredsum32(float v) {
#pragma unroll
  for (int o = 16; o > 0; o >>= 1) v += __shfl_xor(v, o, 64);
  return v;
}

__device__ __forceinline__ float tanh_f(float x) {
  float e = __expf(2.0f * x);
  return 1.0f - 2.0f / (e + 1.0f);
}
__device__ __forceinline__ float sigmoid_f(float x) { return 1.0f / (1.0f + __expf(-x)); }

__device__ __forceinline__ size_t nb_base(int row) {
  return (row < NROW) ? (size_t)row * CAP
                      : (size_t)NROW * CAP + (size_t)(row - NROW) * NB2CAP;
}

// ---- fused pre (512 threads/block): unchanged ----
#define ENC2B (NROW / 64)   // 150
#define CSR2B (NKROW / 8)   // 2400
__global__ void __launch_bounds__(512) k_pre(
    const float* __restrict__ nb, int* __restrict__ nb_cols, int* __restrict__ nb_cnt,
    const float* __restrict__ emb, const float* __restrict__ feat,
    const float* __restrict__ w0, const float* __restrict__ b0,
    const float* __restrict__ w1, const float* __restrict__ b1,
    float* __restrict__ enc0,
    int* __restrict__ col_cnt, float* __restrict__ out, int out_size) {
  __shared__ float Xe[64][25];
  __shared__ float Ht[64][65];
  __shared__ int colS[8][NB2CAP];
  int bid = blockIdx.x;
  int tid = threadIdx.x;
  if (bid < ENC2B) {
    int tile0 = bid * 64;
    if (tid < 256) {
      int i = tid >> 2, f = tid & 3;
      float4 e4 = *(const float4*)(emb + (size_t)(tile0 + i) * 16 + f * 4);
      Xe[i][f * 4] = e4.x; Xe[i][f * 4 + 1] = e4.y; Xe[i][f * 4 + 2] = e4.z; Xe[i][f * 4 + 3] = e4.w;
    } else if (tid < 384) {
      int t = tid - 256; int i = t >> 1, f = t & 1;
      float4 f4 = *(const float4*)(feat + (size_t)(tile0 + i) * 8 + f * 4);
      Xe[i][16 + f * 4] = f4.x; Xe[i][16 + f * 4 + 1] = f4.y;
      Xe[i][16 + f * 4 + 2] = f4.z; Xe[i][16 + f * 4 + 3] = f4.w;
    }
    __syncthreads();
    int rsub = tid >> 4, cg = tid & 15;
    int c0 = cg * 4, r0 = rsub * 2;
    float a[2][4];
#pragma unroll
    for (int i = 0; i < 2; ++i)
#pragma unroll
      for (int j = 0; j < 4; ++j) a[i][j] = b0[c0 + j];
#pragma unroll
    for (int kk = 0; kk < 24; ++kk) {
      float4 w4 = *(const float4*)(w0 + kk * DD + c0);
      float x0 = Xe[r0][kk], x1 = Xe[r0 + 1][kk];
      a[0][0] = fmaf(x0, w4.x, a[0][0]); a[0][1] = fmaf(x0, w4.y, a[0][1]);
      a[0][2] = fmaf(x0, w4.z, a[0][2]); a[0][3] = fmaf(x0, w4.w, a[0][3]);
      a[1][0] = fmaf(x1, w4.x, a[1][0]); a[1][1] = fmaf(x1, w4.y, a[1][1]);
      a[1][2] = fmaf(x1, w4.z, a[1][2]); a[1][3] = fmaf(x1, w4.w, a[1][3]);
    }
#pragma unroll
    for (int i = 0; i < 2; ++i) {
      Ht[r0 + i][c0] = tanh_f(a[i][0]); Ht[r0 + i][c0 + 1] = tanh_f(a[i][1]);
      Ht[r0 + i][c0 + 2] = tanh_f(a[i][2]); Ht[r0 + i][c0 + 3] = tanh_f(a[i][3]);
    }
    __syncthreads();
    float g[2][4];
#pragma unroll
    for (int i = 0; i < 2; ++i)
#pragma unroll
      for (int j = 0; j < 4; ++j) g[i][j] = b1[c0 + j];
#pragma unroll 8
    for (int kk = 0; kk < DD; ++kk) {
      float4 w4 = *(const float4*)(w1 + kk * DD + c0);
      float x0 = Ht[r0][kk], x1 = Ht[r0 + 1][kk];
      g[0][0] = fmaf(x0, w4.x, g[0][0]); g[0][1] = fmaf(x0, w4.y, g[0][1]);
      g[0][2] = fmaf(x0, w4.z, g[0][2]); g[0][3] = fmaf(x0, w4.w, g[0][3]);
      g[1][0] = fmaf(x1, w4.x, g[1][0]); g[1][1] = fmaf(x1, w4.y, g[1][1]);
      g[1][2] = fmaf(x1, w4.z, g[1][2]); g[1][3] = fmaf(x1, w4.w, g[1][3]);
    }
#pragma unroll
    for (int i = 0; i < 2; ++i) {
      float4 o;
      o.x = tanh_f(g[i][0]); o.y = tanh_f(g[i][1]);
      o.z = tanh_f(g[i][2]); o.w = tanh_f(g[i][3]);
      *(float4*)(enc0 + (size_t)(tile0 + r0 + i) * DD + c0) = o;
    }
  } else if (bid < ENC2B + CSR2B) {
    int w = tid >> 6, lane = tid & 63;
    int row = (bid - ENC2B) * 8 + w;       // [0, NKROW)
    const float4* nb4 = (const float4*)(nb + (size_t)row * VV);
    float4 v[5];
#pragma unroll
    for (int c = 0; c < 4; ++c) v[c] = nb4[c * 64 + lane];
    v[4].x = v[4].y = v[4].z = v[4].w = 0.0f;
    if (lane < 44) v[4] = nb4[256 + lane];   // 300 float4 per row
    unsigned long long ltmask = (lane == 0) ? 0ull : ((1ull << lane) - 1ull);
    size_t base = nb_base(row);
    int cap = (row < NROW) ? CAP : NB2CAP;
    int off_base = 0;
#pragma unroll
    for (int c = 0; c < 5; ++c) {
      int nz0 = (v[c].x != 0.0f), nz1 = (v[c].y != 0.0f);
      int nz2 = (v[c].z != 0.0f), nz3 = (v[c].w != 0.0f);
      unsigned long long m0 = __ballot(nz0 != 0);
      unsigned long long m1 = __ballot(nz1 != 0);
      unsigned long long m2 = __ballot(nz2 != 0);
      unsigned long long m3 = __ballot(nz3 != 0);
      int lanepref = __popcll(m0 & ltmask) + __popcll(m1 & ltmask)
                   + __popcll(m2 & ltmask) + __popcll(m3 & ltmask);
      int chunkcnt = __popcll(m0) + __popcll(m1) + __popcll(m2) + __popcll(m3);
      int off = off_base + lanepref;
      int vi = (c * 64 + lane) * 4;
      if (nz0 && off < cap) colS[w][off] = vi;
      off += nz0;
      if (nz1 && off < cap) colS[w][off] = vi + 1;
      off += nz1;
      if (nz2 && off < cap) colS[w][off] = vi + 2;
      off += nz2;
      if (nz3 && off < cap) colS[w][off] = vi + 3;
      off_base += chunkcnt;
    }
    int ncp = (off_base > cap) ? cap : off_base;
    if (lane == 0) nb_cnt[row] = ncp;
    for (int j = lane; j < ncp; j += 64) nb_cols[base + j] = colS[w][j];
  } else {
    for (int i = tid; i < NROW; i += 512) col_cnt[i] = 0;
    if (tid < out_size) out[tid] = 0.0f;
  }
}

// ---- gather: wave per row, 4800 blocks, f32 enc (float4/lane): unchanged ----
__global__ void __launch_bounds__(256) k_gather(
    const int* __restrict__ nb_cols, const int* __restrict__ nb_cnt,
    const float* __restrict__ encIn, float* __restrict__ msg) {
  int w = threadIdx.x >> 6, lane = threadIdx.x & 63;
  int row = blockIdx.x * 4 + w;           // [0, NKROW)
  int k = (row >= NROW) ? 1 : 0;
  int bv = row - k * NROW;
  int b = bv / VV;
  const float4* encF = (const float4*)(encIn + (size_t)b * VV * DD);
  const int* cols = nb_cols + nb_base(row);
  int n = nb_cnt[row];
  int sub = lane >> 4, q = lane & 15;
  float ax = 0.0f, ay = 0.0f, az = 0.0f, aw = 0.0f;
  int j = 0;
  int cc0 = 0, cc1 = 0, cc2 = 0, cc3 = 0;
  if (j + 16 <= n) {
    cc0 = cols[j + sub]; cc1 = cols[j + 4 + sub];
    cc2 = cols[j + 8 + sub]; cc3 = cols[j + 12 + sub];
  }
  while (j + 16 <= n) {
    int nj = j + 16;
    int p0 = 0, p1 = 0, p2 = 0, p3 = 0;
    if (nj + 16 <= n) {
      p0 = cols[nj + sub]; p1 = cols[nj + 4 + sub];
      p2 = cols[nj + 8 + sub]; p3 = cols[nj + 12 + sub];
    }
    float4 u0 = encF[(size_t)cc0 * 16 + q];
    float4 u1 = encF[(size_t)cc1 * 16 + q];
    float4 u2 = encF[(size_t)cc2 * 16 + q];
    float4 u3 = encF[(size_t)cc3 * 16 + q];
    ax += (u0.x + u1.x) + (u2.x + u3.x);
    ay += (u0.y + u1.y) + (u2.y + u3.y);
    az += (u0.z + u1.z) + (u2.z + u3.z);
    aw += (u0.w + u1.w) + (u2.w + u3.w);
    cc0 = p0; cc1 = p1; cc2 = p2; cc3 = p3;
    j = nj;
  }
  for (; j < n; j += 4) {
    int idx = j + sub;
    if (idx < n) {
      float4 u = encF[(size_t)cols[idx] * 16 + q];
      ax += u.x; ay += u.y; az += u.z; aw += u.w;
    }
  }
#pragma unroll
  for (int o = 16; o < 64; o <<= 1) {
    ax += __shfl_xor(ax, o, 64);
    ay += __shfl_xor(ay, o, 64);
    az += __shfl_xor(az, o, 64);
    aw += __shfl_xor(aw, o, 64);
  }
  if (lane < 16) {
    float inv = 1.0f / fmaxf((float)n, 1.0f);
    float4 r; r.x = ax * inv; r.y = ay * inv; r.z = az * inv; r.w = aw * inv;
    ((float4*)(msg + (size_t)row * DD))[q] = r;
  }
}

// ---- fused layer, 16KB K-split weight staging with T14 register prefetch:
// each phase issues the NEXT stage's global loads before computing, and commits
// regs->WS after the post-compute barrier. Stage L2 latency hides under compute.
// grid = NROW/16 = 600 blocks, 256 thr, LDS ~33.5KB -> 4 blocks/CU.
__global__ void __launch_bounds__(256) k_layer(
    const float* __restrict__ msg, const float* __restrict__ encIn,
    const float* __restrict__ agg_w, const float* __restrict__ agg_b,
    const float* __restrict__ att_w, const float* __restrict__ att_b,
    const float* __restrict__ att_v,
    const float* __restrict__ wu, const float* __restrict__ bu,
    const float* __restrict__ wr, const float* __restrict__ br,
    const float* __restrict__ wc, const float* __restrict__ bc,
    float* __restrict__ encOut,
    int do_decode,
    const float* __restrict__ dw0, const float* __restrict__ db0,
    const float* __restrict__ dw1, const float* __restrict__ db1,
    const float* __restrict__ uw0, const float* __restrict__ ub0,
    const float* __restrict__ uw1, const float* __restrict__ ub1,
    float* __restrict__ pred, float* __restrict__ dualp) {
  __shared__ float MG[32][65];       // msg tile -> G in-place -> rows 0..15 reused as EO
  __shared__ float X[16][129];
  __shared__ float scS[NH][KH][16];
  __shared__ float WS[4096];         // 16KB weight staging
  int tid = threadIdx.x;
  int t0 = blockIdx.x * 16;
  int strip = tid >> 5, cg2 = tid & 31;
  int c0 = cg2 * 2;
  int r0 = strip * 4;                 // [0,32): strips 0-3 hop1, 4-7 hop2
  int gr0 = strip * 2;                // [0,16)
  int k = strip >> 2;
  float4 pf[4];
  // ---- issue S0 (agg K-half 0, both hops) ----
#pragma unroll
  for (int p = 0; p < 4; ++p) {
    int idx = p * 256 + tid; int k2 = idx >> 9, o4 = idx & 511;
    pf[p] = ((const float4*)(agg_w + k2 * 4096))[o4];
  }
  // ---- load msg tile (overlaps S0 latency) ----
#pragma unroll
  for (int rep = 0; rep < 2; ++rep) {
    int idx = rep * 256 + tid; int i = idx >> 4, d4 = idx & 15;
    int grow = (i < 16) ? (t0 + i) : (NROW + t0 + (i - 16));
    float4 m4 = *(const float4*)(msg + (size_t)grow * DD + d4 * 4);
    MG[i][d4 * 4] = m4.x; MG[i][d4 * 4 + 1] = m4.y;
    MG[i][d4 * 4 + 2] = m4.z; MG[i][d4 * 4 + 3] = m4.w;
  }
  // ---- commit S0 ----
#pragma unroll
  for (int p = 0; p < 4; ++p) ((float4*)WS)[p * 256 + tid] = pf[p];
  __syncthreads();
  // ---- P0: agg K0-31 (prefetch S1 = agg half 1) ----
#pragma unroll
  for (int p = 0; p < 4; ++p) {
    int idx = p * 256 + tid; int k2 = idx >> 9, o4 = idx & 511;
    pf[p] = ((const float4*)(agg_w + k2 * 4096 + 2048))[o4];
  }
  float acc[4][2];
#pragma unroll
  for (int i = 0; i < 4; ++i) {
    acc[i][0] = agg_b[k * DD + c0]; acc[i][1] = agg_b[k * DD + c0 + 1];
  }
#pragma unroll 8
  for (int kk = 0; kk < 32; ++kk) {
    float2 w2 = *(const float2*)(&WS[k * 2048 + kk * DD + c0]);
#pragma unroll
    for (int i = 0; i < 4; ++i) {
      float x = MG[r0 + i][kk];
      acc[i][0] = fmaf(x, w2.x, acc[i][0]); acc[i][1] = fmaf(x, w2.y, acc[i][1]);
    }
  }
  __syncthreads();
#pragma unroll
  for (int p = 0; p < 4; ++p) ((float4*)WS)[p * 256 + tid] = pf[p];
  __syncthreads();
  // ---- P1: agg K32-63 (prefetch S2 = att head 0) ----
#pragma unroll
  for (int p = 0; p < 4; ++p) pf[p] = ((const float4*)att_w)[p * 256 + tid];
#pragma unroll 8
  for (int kk = 0; kk < 32; ++kk) {
    float2 w2 = *(const float2*)(&WS[k * 2048 + kk * DD + c0]);
#pragma unroll
    for (int i = 0; i < 4; ++i) {
      float x = MG[r0 + i][32 + kk];
      acc[i][0] = fmaf(x, w2.x, acc[i][0]); acc[i][1] = fmaf(x, w2.y, acc[i][1]);
    }
  }
  __syncthreads();                   // MG(msg) + WS reads done
  // ---- write G in-place + commit S2 ----
#pragma unroll
  for (int i = 0; i < 4; ++i) {
    MG[r0 + i][c0] = tanh_f(acc[i][0]);
    MG[r0 + i][c0 + 1] = tanh_f(acc[i][1]);
  }
#pragma unroll
  for (int p = 0; p < 4; ++p) ((float4*)WS)[p * 256 + tid] = pf[p];
  __syncthreads();
  // ---- P2..P5: att heads (prefetch next head, then wu) ----
#pragma unroll
  for (int h = 0; h < NH; ++h) {
    const float* nxt = (h < NH - 1) ? (att_w + (size_t)(h + 1) * 4096) : wu;
#pragma unroll
    for (int p = 0; p < 4; ++p) pf[p] = ((const float4*)nxt)[p * 256 + tid];
    float a2[4][2];
#pragma unroll
    for (int i = 0; i < 4; ++i) {
      a2[i][0] = att_b[h * DD + c0]; a2[i][1] = att_b[h * DD + c0 + 1];
    }
#pragma unroll 8
    for (int kk = 0; kk < DD; ++kk) {
      float2 w2 = *(const float2*)(&WS[kk * DD + c0]);
#pragma unroll
      for (int i = 0; i < 4; ++i) {
        float x = MG[r0 + i][kk];
        a2[i][0] = fmaf(x, w2.x, a2[i][0]); a2[i][1] = fmaf(x, w2.y, a2[i][1]);
      }
    }
    float2 v2 = *(const float2*)(att_v + h * DD + c0);
#pragma unroll
    for (int i = 0; i < 4; ++i) {
      float p = tanh_f(a2[i][0]) * v2.x + tanh_f(a2[i][1]) * v2.y;
      p = gredsum32(p);
      if (cg2 == 0) scS[h][k][(strip & 3) * 4 + i] = p;
    }
    __syncthreads();
#pragma unroll
    for (int p = 0; p < 4; ++p) ((float4*)WS)[p * 256 + tid] = pf[p];
    if (h < NH - 1) __syncthreads();
  }
  // ---- hop-softmax mix -> X (same interval as S6 commit; scS complete) ----
  {
    int i = tid >> 4, d4 = tid & 15;    // 16 rows x 16 d4 = 256
    float W0 = 0.0f, W1 = 0.0f;
#pragma unroll
    for (int h = 0; h < NH; ++h) {
      float s0 = scS[h][0][i];
      float s1 = scS[h][1][i];
      float m = fmaxf(s0, s1);
      float e0 = __expf(s0 - m), e1 = __expf(s1 - m);
      float inv = 1.0f / (e0 + e1);
      W0 += e0 * inv; W1 += e1 * inv;
    }
    W0 *= 0.25f; W1 *= 0.25f;
    float4 ef = *(const float4*)(encIn + (size_t)(t0 + i) * DD + d4 * 4);
#pragma unroll
    for (int j = 0; j < 4; ++j) {
      int d = d4 * 4 + j;
      X[i][d] = W0 * MG[i][d] + W1 * MG[16 + i][d];
    }
    X[i][64 + d4 * 4]     = ef.x;
    X[i][64 + d4 * 4 + 1] = ef.y;
    X[i][64 + d4 * 4 + 2] = ef.z;
    X[i][64 + d4 * 4 + 3] = ef.w;
  }
  __syncthreads();
  // ---- P6: u-gate K0-63 (prefetch S7 = wu half 1) ----
#pragma unroll
  for (int p = 0; p < 4; ++p) pf[p] = ((const float4*)(wu + 64 * DD))[p * 256 + tid];
  float au[2][2];
#pragma unroll
  for (int i = 0; i < 2; ++i) { au[i][0] = bu[c0]; au[i][1] = bu[c0 + 1]; }
#pragma unroll 8
  for (int kk = 0; kk < DD; ++kk) {
    float2 u2 = *(const float2*)(&WS[kk * DD + c0]);
#pragma unroll
    for (int i = 0; i < 2; ++i) {
      float x = X[gr0 + i][kk];
      au[i][0] = fmaf(x, u2.x, au[i][0]); au[i][1] = fmaf(x, u2.y, au[i][1]);
    }
  }
  __syncthreads();
#pragma unroll
  for (int p = 0; p < 4; ++p) ((float4*)WS)[p * 256 + tid] = pf[p];
  __syncthreads();
  // ---- P7: u-gate K64-127 (prefetch S8 = wr half 0) ----
#pragma unroll
  for (int p = 0; p < 4; ++p) pf[p] = ((const float4*)wr)[p * 256 + tid];
#pragma unroll 8
  for (int kk = 0; kk < DD; ++kk) {
    float2 u2 = *(const float2*)(&WS[kk * DD + c0]);
#pragma unroll
    for (int i = 0; i < 2; ++i) {
      float x = X[gr0 + i][64 + kk];
      au[i][0] = fmaf(x, u2.x, au[i][0]); au[i][1] = fmaf(x, u2.y, au[i][1]);
    }
  }
  float uu[2][2], encv[2][2];
#pragma unroll
  for (int i = 0; i < 2; ++i) {
    uu[i][0] = sigmoid_f(au[i][0]); uu[i][1] = sigmoid_f(au[i][1]);
    encv[i][0] = X[gr0 + i][64 + c0]; encv[i][1] = X[gr0 + i][64 + c0 + 1];
  }
  __syncthreads();
#pragma unroll
  for (int p = 0; p < 4; ++p) ((float4*)WS)[p * 256 + tid] = pf[p];
  __syncthreads();
  // ---- P8: r-gate K0-63 (prefetch S9 = wr half 1) ----
#pragma unroll
  for (int p = 0; p < 4; ++p) pf[p] = ((const float4*)(wr + 64 * DD))[p * 256 + tid];
  float ar[2][2];
#pragma unroll
  for (int i = 0; i < 2; ++i) { ar[i][0] = br[c0]; ar[i][1] = br[c0 + 1]; }
#pragma unroll 8
  for (int kk = 0; kk < DD; ++kk) {
    float2 r2 = *(const float2*)(&WS[kk * DD + c0]);
#pragma unroll
    for (int i = 0; i < 2; ++i) {
      float x = X[gr0 + i][kk];
      ar[i][0] = fmaf(x, r2.x, ar[i][0]); ar[i][1] = fmaf(x, r2.y, ar[i][1]);
    }
  }
  __syncthreads();
#pragma unroll
  for (int p = 0; p < 4; ++p) ((float4*)WS)[p * 256 + tid] = pf[p];
  __syncthreads();
  // ---- P9: r-gate K64-127 (prefetch S10 = wc half 0) ----
#pragma unroll
  for (int p = 0; p < 4; ++p) pf[p] = ((const float4*)wc)[p * 256 + tid];
#pragma unroll 8
  for (int kk = 0; kk < DD; ++kk) {
    float2 r2 = *(const float2*)(&WS[kk * DD + c0]);
#pragma unroll
    for (int i = 0; i < 2; ++i) {
      float x = X[gr0 + i][64 + kk];
      ar[i][0] = fmaf(x, r2.x, ar[i][0]); ar[i][1] = fmaf(x, r2.y, ar[i][1]);
    }
  }
  __syncthreads();                   // all X enc-half reads done
  // ---- apply r-gate + commit S10 ----
#pragma unroll
  for (int i = 0; i < 2; ++i) {
    X[gr0 + i][64 + c0]     = encv[i][0] * sigmoid_f(ar[i][0]);
    X[gr0 + i][64 + c0 + 1] = encv[i][1] * sigmoid_f(ar[i][1]);
  }
#pragma unroll
  for (int p = 0; p < 4; ++p) ((float4*)WS)[p * 256 + tid] = pf[p];
  __syncthreads();
  // ---- P10: c-gate K0-63 (prefetch S11 = wc half 1) ----
#pragma unroll
  for (int p = 0; p < 4; ++p) pf[p] = ((const float4*)(wc + 64 * DD))[p * 256 + tid];
  float ac[2][2];
#pragma unroll
  for (int i = 0; i < 2; ++i) { ac[i][0] = bc[c0]; ac[i][1] = bc[c0 + 1]; }
#pragma unroll 8
  for (int kk = 0; kk < DD; ++kk) {
    float2 c2 = *(const float2*)(&WS[kk * DD + c0]);
#pragma unroll
    for (int i = 0; i < 2; ++i) {
      float x = X[gr0 + i][kk];
      ac[i][0] = fmaf(x, c2.x, ac[i][0]); ac[i][1] = fmaf(x, c2.y, ac[i][1]);
    }
  }
  __syncthreads();
#pragma unroll
  for (int p = 0; p < 4; ++p) ((float4*)WS)[p * 256 + tid] = pf[p];
  __syncthreads();
  // ---- P11: c-gate K64-127 (prefetch S12 = dw0 if decode) ----
  if (do_decode) {
#pragma unroll
    for (int p = 0; p < 4; ++p) pf[p] = ((const float4*)dw0)[p * 256 + tid];
  }
#pragma unroll 8
  for (int kk = 0; kk < DD; ++kk) {
    float2 c2 = *(const float2*)(&WS[kk * DD + c0]);
#pragma unroll
    for (int i = 0; i < 2; ++i) {
      float x = X[gr0 + i][64 + kk];
      ac[i][0] = fmaf(x, c2.x, ac[i][0]); ac[i][1] = fmaf(x, c2.y, ac[i][1]);
    }
  }
  // ---- combine -> encOut + EO (aliased onto MG rows 0..15) ----
#pragma unroll
  for (int i = 0; i < 2; ++i) {
    float e0 = uu[i][0] * encv[i][0] + (1.0f - uu[i][0]) * tanh_f(ac[i][0]);
    float e1 = uu[i][1] * encv[i][1] + (1.0f - uu[i][1]) * tanh_f(ac[i][1]);
    *(float2*)(encOut + (size_t)(t0 + gr0 + i) * DD + c0) = make_float2(e0, e1);
    MG[gr0 + i][c0] = e0; MG[gr0 + i][c0 + 1] = e1;
  }
  if (do_decode) {
    __syncthreads();                 // EO(MG) complete + WS(wc) reads done
#pragma unroll
    for (int p = 0; p < 4; ++p) ((float4*)WS)[p * 256 + tid] = pf[p];
    __syncthreads();
    // ---- P12: decode hd (prefetch S13 = uw0) ----
#pragma unroll
    for (int p = 0; p < 4; ++p) pf[p] = ((const float4*)uw0)[p * 256 + tid];
    float hd[2][2], hq[2][2];
#pragma unroll
    for (int i = 0; i < 2; ++i) {
      hd[i][0] = db0[c0]; hd[i][1] = db0[c0 + 1];
      hq[i][0] = ub0[c0]; hq[i][1] = ub0[c0 + 1];
    }
#pragma unroll 8
    for (int kk = 0; kk < DD; ++kk) {
      float2 d2 = *(const float2*)(&WS[kk * DD + c0]);
#pragma unroll
      for (int i = 0; i < 2; ++i) {
        float x = MG[gr0 + i][kk];
        hd[i][0] = fmaf(x, d2.x, hd[i][0]); hd[i][1] = fmaf(x, d2.y, hd[i][1]);
      }
    }
    __syncthreads();
#pragma unroll
    for (int p = 0; p < 4; ++p) ((float4*)WS)[p * 256 + tid] = pf[p];
    __syncthreads();
    // ---- P13: decode hq ----
#pragma unroll 8
    for (int kk = 0; kk < DD; ++kk) {
      float2 q2 = *(const float2*)(&WS[kk * DD + c0]);
#pragma unroll
      for (int i = 0; i < 2; ++i) {
        float x = MG[gr0 + i][kk];
        hq[i][0] = fmaf(x, q2.x, hq[i][0]); hq[i][1] = fmaf(x, q2.y, hq[i][1]);
      }
    }
    float2 dv = *(const float2*)(dw1 + c0);
    float2 qv = *(const float2*)(uw1 + c0);
#pragma unroll
    for (int i = 0; i < 2; ++i) {
      float p = hd[i][0] * dv.x + hd[i][1] * dv.y;
      float q = hq[i][0] * qv.x + hq[i][1] * qv.y;
      p = gredsum32(p);
      q = gredsum32(q);
      if (cg2 == 0) {
        pred[t0 + gr0 + i] = p + db1[0];
        dualp[t0 + gr0 + i] = q + ub1[0];
      }
    }
  }
}

// ------- fused: sparsemax (fixed-point tau) + CSC scatter + dual edge cost -------
__global__ void __launch_bounds__(256) k_primal_dual(
    const int* __restrict__ nb_cols, const int* __restrict__ nb_cnt,
    const float* __restrict__ pred, const float* __restrict__ dualp,
    const float* __restrict__ dem,
    float* __restrict__ rowsum,
    int* __restrict__ col_cnt, int* __restrict__ col_rows, float* __restrict__ col_vals,
    float* __restrict__ out) {
  __shared__ float bacc[BB];
  if (threadIdx.x < BB) bacc[threadIdx.x] = 0.0f;
  __syncthreads();
  int w = threadIdx.x >> 6, lane = threadIdx.x & 63;
  int row = blockIdx.x * 4 + w;
  int b = row / VV;
  int n = nb_cnt[row];
  int c = (lane < n) ? nb_cols[(size_t)row * CAP + lane] : 0;
  const float* predB = pred + (size_t)b * VV;
  const float* dualB = dualp + (size_t)b * VV;
  float z = (lane < n) ? predB[c] : -1e30f;
  float tau = 0.0f;
  if (n > 0) {
    bool in = (lane < n);
    for (int it = 0; it < 64; ++it) {
      float s = wredsum(in ? z : 0.0f);
      int cnt = (int)__popcll(__ballot(in));
      tau = (s - 1.0f) / (float)cnt;
      bool nin = (z > tau);
      if (__ballot(nin) == __ballot(in)) break;
      in = nin;
    }
  }
  float pv = (lane < n) ? fmaxf(z - tau, 0.0f) : 0.0f;
  float s2 = wredsum(pv * pv);
  if (lane == 0) rowsum[row] = s2;
  if (pv > 0.0f) {
    int g = b * VV + c;
    int j = atomicAdd(&col_cnt[g], 1);
    if (j < CAP) {
      col_rows[(size_t)g * CAP + j] = row - b * VV;
      col_vals[(size_t)g * CAP + j] = pv;
    }
  }
  float du = dualp[row];
  float es = 0.0f;
  if (lane < n) {
    float dd = du - dualB[c];
    float f = 0.0f, acm = 0.0f;
#pragma unroll
    for (int t = 0; t < 8; ++t) {
      float look = f - 0.9f * acm;
      float grad = 2.0f * look - dd;
      acm = 0.9f * acm + 0.1f * grad;
      f = fmaxf(f - acm, 0.0f);
    }
    es = f * f - dd * f;
  }
  float contrib = -es;
  if (lane == 0) contrib += du * dem[row];
  float ws_ = wredsum(contrib);
  if (lane == 0) atomicAdd(&bacc[b], ws_);
  __syncthreads();
  if (threadIdx.x < BB) {
    float t = bacc[threadIdx.x];
    if (t != 0.0f) atomicAdd(&out[threadIdx.x], t);
  }
}

// ------- fused flow iterations (per-graph block) + flow cost -------
__global__ void __launch_bounds__(1024) k_flow(
    const int* __restrict__ col_cnt, const int* __restrict__ col_rows,
    const float* __restrict__ col_vals, const float* __restrict__ dem,
    const float* __restrict__ rowsum, float* __restrict__ out) {
  __shared__ float aS[VV];
  __shared__ float red[16];
  int b = blockIdx.x;
  int tid = threadIdx.x;
  const float* demB = dem + (size_t)b * VV;
  for (int v = tid; v < VV; v += 1024) aS[v] = fmaxf(-demB[v], 0.0f);
  __syncthreads();
  for (int t = 0; t < 7; ++t) {
    float nv0 = 0.0f, nv1 = 0.0f;
    {
      int v = tid;
      if (v < VV) {
        int g = b * VV + v;
        int n = col_cnt[g]; if (n > CAP) n = CAP;
        const int* cr = col_rows + (size_t)g * CAP;
        const float* cv = col_vals + (size_t)g * CAP;
        float acc = 0.0f;
        for (int j = 0; j < n; ++j) acc += cv[j] * aS[cr[j]];
        nv0 = fmaxf(acc - demB[v], 0.0f);
      }
      v = tid + 1024;
      if (v < VV) {
        int g = b * VV + v;
        int n = col_cnt[g]; if (n > CAP) n = CAP;
        const int* cr = col_rows + (size_t)g * CAP;
        const float* cv = col_vals + (size_t)g * CAP;
        float acc = 0.0f;
        for (int j = 0; j < n; ++j) acc += cv[j] * aS[cr[j]];
        nv1 = fmaxf(acc - demB[v], 0.0f);
      }
    }
    __syncthreads();
    if (tid < VV) aS[tid] = nv0;
    if (tid + 1024 < VV) aS[tid + 1024] = nv1;
    __syncthreads();
  }
  float fc = 0.0f;
  for (int v = tid; v < VV; v += 1024) { float a = aS[v]; fc += a * a * rowsum[b * VV + v]; }
  fc = wredsum(fc);
  int wid = tid >> 6, lane = tid & 63;
  if (lane == 0) red[wid] = fc;
  __syncthreads();
  if (tid == 0) {
    float s = 0.0f;
#pragma unroll
    for (int i = 0; i < 16; ++i) s += red[i];
    atomicAdd(&out[b], s);
  }
}

extern "C" void kernel_launch(void* const* d_in, const int* in_sizes, int n_in,
                              void* d_out, int out_size, void* d_ws, size_t ws_size,
                              hipStream_t stream) {
  const float* feat   = (const float*)d_in[0];
  const float* emb    = (const float*)d_in[1];
  const float* dem    = (const float*)d_in[2];
  const float* nb     = (const float*)d_in[4];   // [K,B,V,V]
  const float* enc_w0 = (const float*)d_in[5];
  const float* enc_b0 = (const float*)d_in[6];
  const float* enc_w1 = (const float*)d_in[7];
  const float* enc_b1 = (const float*)d_in[8];
  const float* agg_w  = (const float*)d_in[9];
  const float* agg_b  = (const float*)d_in[10];
  const float* att_w  = (const float*)d_in[11];
  const float* att_b  = (const float*)d_in[12];
  const float* att_v  = (const float*)d_in[13];
  const float* gru_wu = (const float*)d_in[14];
  const float* gru_bu = (const float*)d_in[15];
  const float* gru_wr = (const float*)d_in[16];
  const float* gru_br = (const float*)d_in[17];
  const float* gru_wc = (const float*)d_in[18];
  const float* gru_bc = (const float*)d_in[19];
  const float* dec_w0 = (const float*)d_in[20];
  const float* dec_b0 = (const float*)d_in[21];
  const float* dec_w1 = (const float*)d_in[22];
  const float* dec_b1 = (const float*)d_in[23];
  const float* dual_w0= (const float*)d_in[24];
  const float* dual_b0= (const float*)d_in[25];
  const float* dual_w1= (const float*)d_in[26];
  const float* dual_b1= (const float*)d_in[27];
  float* out = (float*)d_out;

  float* enc0 = (float*)d_ws;                            // NROW*DD f32
  float* enc1 = enc0 + (size_t)NROW * DD;
  float* msg      = enc1 + (size_t)NROW * DD;            // NKROW*DD
  float* pred     = msg + (size_t)NKROW * DD;
  float* dualp    = pred + NROW;
  float* rowsum   = dualp + NROW;
  float* col_vals = rowsum + NROW;                       // NROW*CAP
  int* col_cnt  = (int*)(col_vals + (size_t)NROW * CAP);
  int* nb_cnt   = col_cnt + NROW;                        // NKROW
  int* col_rows = nb_cnt + NKROW;                        // NROW*CAP
  int* nb_cols  = col_rows + (size_t)NROW * CAP;

  (void)in_sizes; (void)n_in; (void)ws_size;

  k_pre<<<ENC2B + CSR2B + 1, 512, 0, stream>>>(
      nb, nb_cols, nb_cnt, emb, feat, enc_w0, enc_b0, enc_w1, enc_b1, enc0,
      col_cnt, out, out_size);

  const float* encIn = enc0;
  float* encOut = enc1;
  for (int l = 0; l < 2; ++l) {
    k_gather<<<NKROW / 4, 256, 0, stream>>>(nb_cols, nb_cnt, encIn, msg);
    k_layer<<<NROW / 16, 256, 0, stream>>>(msg, encIn,
                                           agg_w, agg_b, att_w, att_b, att_v,
                                           gru_wu, gru_bu, gru_wr, gru_br, gru_wc, gru_bc,
                                           encOut,
                                           (l == 1) ? 1 : 0,
                                           dec_w0, dec_b0, dec_w1, dec_b1,
                                           dual_w0, dual_b0, dual_w1, dual_b1, pred, dualp);
    const float* t = encIn; encIn = encOut; encOut = (float*)t;
  }

  k_primal_dual<<<NROW / 4, 256, 0, stream>>>(nb_cols, nb_cnt, pred, dualp, dem,
                                              rowsum, col_cnt, col_rows, col_vals, out);
  k_flow<<<BB, 1024, 0, stream>>>(col_cnt, col_rows, col_vals, dem, rowsum, out);
}

// Round 14
// 469.535 us; speedup vs baseline: 1.0602x; 1.0602x over previous
//
#include <hip/hip_runtime.h>

#define BB 8
#define VV 1200
#define DD 64
#define KH 2     // hops
#define NH 4     // heads
#define CAP 64        // hop1 cap
#define NB2CAP 384    // hop2 cap
#define NROW (BB*VV)          // 9600
#define NKROW (KH*BB*VV)      // 19200

// packed bf16 weight buffer layout (uint = bf16x2 pair along columns)
#define AGGP 0        // 4096 uints: [hop][64][32]
#define ATTP 4096     // 8192 uints: [head][64][32]
#define WUP  12288    // 4096 uints: [128][32]
#define WRP  16384    // 4096
#define WCP  20480    // 4096
#define DECP 24576    // 4096: dw0 [64][32] then uw0 [64][32]
#define WPACK_N 28672

__device__ __forceinline__ float wredsum(float v) {
#pragma unroll
  for (int o = 32; o > 0; o >>= 1) v += __shfl_xor(v, o, 64);
  return v;
}
// reduce across 32-lane groups
__device__ __forceinline__ float gredsum32(float v) {
#pragma unroll
  for (int o = 16; o > 0; o >>= 1) v += __shfl_xor(v, o, 64);
  return v;
}

__device__ __forceinline__ float tanh_f(float x) {
  float e = __expf(2.0f * x);
  return 1.0f - 2.0f / (e + 1.0f);
}
__device__ __forceinline__ float sigmoid_f(float x) { return 1.0f / (1.0f + __expf(-x)); }

// bf16 pack/unpack (RNE)
__device__ __forceinline__ unsigned pack_bf16x2(float a, float b) {
  unsigned ua = __float_as_uint(a), ub = __float_as_uint(b);
  ua = (ua + 0x7fffu + ((ua >> 16) & 1u)) >> 16;
  ub = (ub + 0x7fffu + ((ub >> 16) & 1u)) & 0xffff0000u;
  return ua | ub;
}
__device__ __forceinline__ float bf_lo(unsigned u) { return __uint_as_float(u << 16); }
__device__ __forceinline__ float bf_hi(unsigned u) { return __uint_as_float(u & 0xffff0000u); }

__device__ __forceinline__ size_t nb_base(int row) {
  return (row < NROW) ? (size_t)row * CAP
                      : (size_t)NROW * CAP + (size_t)(row - NROW) * NB2CAP;
}

// ---- fused pre (512 threads/block): encoder + CSR + zero/pack tail ----
#define ENC2B (NROW / 64)   // 150
#define CSR2B (NKROW / 8)   // 2400
__global__ void __launch_bounds__(512) k_pre(
    const float* __restrict__ nb, int* __restrict__ nb_cols, int* __restrict__ nb_cnt,
    const float* __restrict__ emb, const float* __restrict__ feat,
    const float* __restrict__ w0, const float* __restrict__ b0,
    const float* __restrict__ w1, const float* __restrict__ b1,
    float* __restrict__ enc0,
    const float* __restrict__ agg_w, const float* __restrict__ att_w,
    const float* __restrict__ wu, const float* __restrict__ wr,
    const float* __restrict__ wc,
    const float* __restrict__ dw0, const float* __restrict__ uw0,
    unsigned* __restrict__ wpack,
    int* __restrict__ col_cnt, float* __restrict__ out, int out_size) {
  __shared__ float Xe[64][25];
  __shared__ float Ht[64][65];
  __shared__ int colS[8][NB2CAP];
  int bid = blockIdx.x;
  int tid = threadIdx.x;
  if (bid < ENC2B) {
    int tile0 = bid * 64;
    if (tid < 256) {
      int i = tid >> 2, f = tid & 3;
      float4 e4 = *(const float4*)(emb + (size_t)(tile0 + i) * 16 + f * 4);
      Xe[i][f * 4] = e4.x; Xe[i][f * 4 + 1] = e4.y; Xe[i][f * 4 + 2] = e4.z; Xe[i][f * 4 + 3] = e4.w;
    } else if (tid < 384) {
      int t = tid - 256; int i = t >> 1, f = t & 1;
      float4 f4 = *(const float4*)(feat + (size_t)(tile0 + i) * 8 + f * 4);
      Xe[i][16 + f * 4] = f4.x; Xe[i][16 + f * 4 + 1] = f4.y;
      Xe[i][16 + f * 4 + 2] = f4.z; Xe[i][16 + f * 4 + 3] = f4.w;
    }
    __syncthreads();
    int rsub = tid >> 4, cg = tid & 15;
    int c0 = cg * 4, r0 = rsub * 2;
    float a[2][4];
#pragma unroll
    for (int i = 0; i < 2; ++i)
#pragma unroll
      for (int j = 0; j < 4; ++j) a[i][j] = b0[c0 + j];
#pragma unroll
    for (int kk = 0; kk < 24; ++kk) {
      float4 w4 = *(const float4*)(w0 + kk * DD + c0);
      float x0 = Xe[r0][kk], x1 = Xe[r0 + 1][kk];
      a[0][0] = fmaf(x0, w4.x, a[0][0]); a[0][1] = fmaf(x0, w4.y, a[0][1]);
      a[0][2] = fmaf(x0, w4.z, a[0][2]); a[0][3] = fmaf(x0, w4.w, a[0][3]);
      a[1][0] = fmaf(x1, w4.x, a[1][0]); a[1][1] = fmaf(x1, w4.y, a[1][1]);
      a[1][2] = fmaf(x1, w4.z, a[1][2]); a[1][3] = fmaf(x1, w4.w, a[1][3]);
    }
#pragma unroll
    for (int i = 0; i < 2; ++i) {
      Ht[r0 + i][c0] = tanh_f(a[i][0]); Ht[r0 + i][c0 + 1] = tanh_f(a[i][1]);
      Ht[r0 + i][c0 + 2] = tanh_f(a[i][2]); Ht[r0 + i][c0 + 3] = tanh_f(a[i][3]);
    }
    __syncthreads();
    float g[2][4];
#pragma unroll
    for (int i = 0; i < 2; ++i)
#pragma unroll
      for (int j = 0; j < 4; ++j) g[i][j] = b1[c0 + j];
#pragma unroll 8
    for (int kk = 0; kk < DD; ++kk) {
      float4 w4 = *(const float4*)(w1 + kk * DD + c0);
      float x0 = Ht[r0][kk], x1 = Ht[r0 + 1][kk];
      g[0][0] = fmaf(x0, w4.x, g[0][0]); g[0][1] = fmaf(x0, w4.y, g[0][1]);
      g[0][2] = fmaf(x0, w4.z, g[0][2]); g[0][3] = fmaf(x0, w4.w, g[0][3]);
      g[1][0] = fmaf(x1, w4.x, g[1][0]); g[1][1] = fmaf(x1, w4.y, g[1][1]);
      g[1][2] = fmaf(x1, w4.z, g[1][2]); g[1][3] = fmaf(x1, w4.w, g[1][3]);
    }
#pragma unroll
    for (int i = 0; i < 2; ++i) {
      float4 o;
      o.x = tanh_f(g[i][0]); o.y = tanh_f(g[i][1]);
      o.z = tanh_f(g[i][2]); o.w = tanh_f(g[i][3]);
      *(float4*)(enc0 + (size_t)(tile0 + r0 + i) * DD + c0) = o;
    }
  } else if (bid < ENC2B + CSR2B) {
    int w = tid >> 6, lane = tid & 63;
    int row = (bid - ENC2B) * 8 + w;       // [0, NKROW)
    const float4* nb4 = (const float4*)(nb + (size_t)row * VV);
    float4 v[5];
#pragma unroll
    for (int c = 0; c < 4; ++c) v[c] = nb4[c * 64 + lane];
    v[4].x = v[4].y = v[4].z = v[4].w = 0.0f;
    if (lane < 44) v[4] = nb4[256 + lane];   // 300 float4 per row
    unsigned long long ltmask = (lane == 0) ? 0ull : ((1ull << lane) - 1ull);
    size_t base = nb_base(row);
    int cap = (row < NROW) ? CAP : NB2CAP;
    int off_base = 0;
#pragma unroll
    for (int c = 0; c < 5; ++c) {
      int nz0 = (v[c].x != 0.0f), nz1 = (v[c].y != 0.0f);
      int nz2 = (v[c].z != 0.0f), nz3 = (v[c].w != 0.0f);
      unsigned long long m0 = __ballot(nz0 != 0);
      unsigned long long m1 = __ballot(nz1 != 0);
      unsigned long long m2 = __ballot(nz2 != 0);
      unsigned long long m3 = __ballot(nz3 != 0);
      int lanepref = __popcll(m0 & ltmask) + __popcll(m1 & ltmask)
                   + __popcll(m2 & ltmask) + __popcll(m3 & ltmask);
      int chunkcnt = __popcll(m0) + __popcll(m1) + __popcll(m2) + __popcll(m3);
      int off = off_base + lanepref;
      int vi = (c * 64 + lane) * 4;
      if (nz0 && off < cap) colS[w][off] = vi;
      off += nz0;
      if (nz1 && off < cap) colS[w][off] = vi + 1;
      off += nz1;
      if (nz2 && off < cap) colS[w][off] = vi + 2;
      off += nz2;
      if (nz3 && off < cap) colS[w][off] = vi + 3;
      off_base += chunkcnt;
    }
    int ncp = (off_base > cap) ? cap : off_base;
    if (lane == 0) nb_cnt[row] = ncp;
    for (int j = lane; j < ncp; j += 64) nb_cols[base + j] = colS[w][j];
  } else {
    for (int i = tid; i < NROW; i += 512) col_cnt[i] = 0;
    if (tid < out_size) out[tid] = 0.0f;
    // pack weights to bf16x2 pairs (column-major pairs, row-major layout)
    for (int i = tid; i < 4096; i += 512)
      wpack[AGGP + i] = pack_bf16x2(agg_w[2 * i], agg_w[2 * i + 1]);
    for (int i = tid; i < 8192; i += 512)
      wpack[ATTP + i] = pack_bf16x2(att_w[2 * i], att_w[2 * i + 1]);
    for (int i = tid; i < 4096; i += 512) {
      wpack[WUP + i] = pack_bf16x2(wu[2 * i], wu[2 * i + 1]);
      wpack[WRP + i] = pack_bf16x2(wr[2 * i], wr[2 * i + 1]);
      wpack[WCP + i] = pack_bf16x2(wc[2 * i], wc[2 * i + 1]);
    }
    for (int i = tid; i < 2048; i += 512) {
      wpack[DECP + i] = pack_bf16x2(dw0[2 * i], dw0[2 * i + 1]);
      wpack[DECP + 2048 + i] = pack_bf16x2(uw0[2 * i], uw0[2 * i + 1]);
    }
  }
}

// ---- gather: wave per row, 4800 blocks, f32 enc (float4/lane): unchanged ----
__global__ void __launch_bounds__(256) k_gather(
    const int* __restrict__ nb_cols, const int* __restrict__ nb_cnt,
    const float* __restrict__ encIn, float* __restrict__ msg) {
  int w = threadIdx.x >> 6, lane = threadIdx.x & 63;
  int row = blockIdx.x * 4 + w;           // [0, NKROW)
  int k = (row >= NROW) ? 1 : 0;
  int bv = row - k * NROW;
  int b = bv / VV;
  const float4* encF = (const float4*)(encIn + (size_t)b * VV * DD);
  const int* cols = nb_cols + nb_base(row);
  int n = nb_cnt[row];
  int sub = lane >> 4, q = lane & 15;
  float ax = 0.0f, ay = 0.0f, az = 0.0f, aw = 0.0f;
  int j = 0;
  int cc0 = 0, cc1 = 0, cc2 = 0, cc3 = 0;
  if (j + 16 <= n) {
    cc0 = cols[j + sub]; cc1 = cols[j + 4 + sub];
    cc2 = cols[j + 8 + sub]; cc3 = cols[j + 12 + sub];
  }
  while (j + 16 <= n) {
    int nj = j + 16;
    int p0 = 0, p1 = 0, p2 = 0, p3 = 0;
    if (nj + 16 <= n) {
      p0 = cols[nj + sub]; p1 = cols[nj + 4 + sub];
      p2 = cols[nj + 8 + sub]; p3 = cols[nj + 12 + sub];
    }
    float4 u0 = encF[(size_t)cc0 * 16 + q];
    float4 u1 = encF[(size_t)cc1 * 16 + q];
    float4 u2 = encF[(size_t)cc2 * 16 + q];
    float4 u3 = encF[(size_t)cc3 * 16 + q];
    ax += (u0.x + u1.x) + (u2.x + u3.x);
    ay += (u0.y + u1.y) + (u2.y + u3.y);
    az += (u0.z + u1.z) + (u2.z + u3.z);
    aw += (u0.w + u1.w) + (u2.w + u3.w);
    cc0 = p0; cc1 = p1; cc2 = p2; cc3 = p3;
    j = nj;
  }
  for (; j < n; j += 4) {
    int idx = j + sub;
    if (idx < n) {
      float4 u = encF[(size_t)cols[idx] * 16 + q];
      ax += u.x; ay += u.y; az += u.z; aw += u.w;
    }
  }
#pragma unroll
  for (int o = 16; o < 64; o <<= 1) {
    ax += __shfl_xor(ax, o, 64);
    ay += __shfl_xor(ay, o, 64);
    az += __shfl_xor(az, o, 64);
    aw += __shfl_xor(aw, o, 64);
  }
  if (lane < 16) {
    float inv = 1.0f / fmaxf((float)n, 1.0f);
    float4 r; r.x = ax * inv; r.y = ay * inv; r.z = az * inv; r.w = aw * inv;
    ((float4*)(msg + (size_t)row * DD))[q] = r;
  }
}

// ---- fused layer, bf16-packed weight staging (16KB = full matrices).
// 7 stage phases (vs 14): agg(1) att(2) wu/wr/wc(3) dec(1). Sync staging, no
// register prefetch (round-13 lesson: pf regs spill to scratch).
// grid = NROW/16 = 600 blocks, 256 thr, LDS ~33.5KB -> 4 blocks/CU.
__global__ void __launch_bounds__(256) k_layer(
    const float* __restrict__ msg, const float* __restrict__ encIn,
    const unsigned* __restrict__ wpack,
    const float* __restrict__ agg_b, const float* __restrict__ att_b,
    const float* __restrict__ att_v,
    const float* __restrict__ bu, const float* __restrict__ br,
    const float* __restrict__ bc,
    float* __restrict__ encOut,
    int do_decode,
    const float* __restrict__ db0, const float* __restrict__ dw1,
    const float* __restrict__ db1,
    const float* __restrict__ ub0, const float* __restrict__ uw1,
    const float* __restrict__ ub1,
    float* __restrict__ pred, float* __restrict__ dualp) {
  __shared__ float MG[32][65];       // msg tile -> G in-place -> rows 0..15 reused as EO
  __shared__ float X[16][129];
  __shared__ float scS[NH][KH][16];
  __shared__ unsigned WSu[4096];     // 16KB packed-weight staging (8192 bf16)
  int tid = threadIdx.x;
  int t0 = blockIdx.x * 16;
  int strip = tid >> 5, cg2 = tid & 31;
  int c0 = cg2 * 2;
  int r0 = strip * 4;                 // [0,32): strips 0-3 hop1, 4-7 hop2
  int gr0 = strip * 2;                // [0,16)
  int k = strip >> 2;
  // ---- stage aggP (both hops) + load msg tile ----
#pragma unroll
  for (int p = 0; p < 4; ++p)
    ((uint4*)WSu)[p * 256 + tid] = ((const uint4*)(wpack + AGGP))[p * 256 + tid];
#pragma unroll
  for (int rep = 0; rep < 2; ++rep) {
    int idx = rep * 256 + tid; int i = idx >> 4, d4 = idx & 15;
    int grow = (i < 16) ? (t0 + i) : (NROW + t0 + (i - 16));
    float4 m4 = *(const float4*)(msg + (size_t)grow * DD + d4 * 4);
    MG[i][d4 * 4] = m4.x; MG[i][d4 * 4 + 1] = m4.y;
    MG[i][d4 * 4 + 2] = m4.z; MG[i][d4 * 4 + 3] = m4.w;
  }
  __syncthreads();
  // ---- agg GEMM, full K=64 ----
  float acc[4][2];
#pragma unroll
  for (int i = 0; i < 4; ++i) {
    acc[i][0] = agg_b[k * DD + c0]; acc[i][1] = agg_b[k * DD + c0 + 1];
  }
#pragma unroll 8
  for (int kk = 0; kk < DD; ++kk) {
    unsigned u = WSu[k * 2048 + kk * 32 + cg2];
    float wx = bf_lo(u), wy = bf_hi(u);
#pragma unroll
    for (int i = 0; i < 4; ++i) {
      float x = MG[r0 + i][kk];
      acc[i][0] = fmaf(x, wx, acc[i][0]); acc[i][1] = fmaf(x, wy, acc[i][1]);
    }
  }
  __syncthreads();                   // MG(msg) + WSu reads done
  // ---- write G in-place + stage att heads 0,1 ----
#pragma unroll
  for (int i = 0; i < 4; ++i) {
    MG[r0 + i][c0] = tanh_f(acc[i][0]);
    MG[r0 + i][c0 + 1] = tanh_f(acc[i][1]);
  }
#pragma unroll
  for (int p = 0; p < 4; ++p)
    ((uint4*)WSu)[p * 256 + tid] = ((const uint4*)(wpack + ATTP))[p * 256 + tid];
  __syncthreads();
  // ---- att heads (2 per stage) ----
#pragma unroll
  for (int pr = 0; pr < 2; ++pr) {
#pragma unroll
    for (int h = 0; h < 2; ++h) {
      int hh = pr * 2 + h;
      float a2[4][2];
#pragma unroll
      for (int i = 0; i < 4; ++i) {
        a2[i][0] = att_b[hh * DD + c0]; a2[i][1] = att_b[hh * DD + c0 + 1];
      }
#pragma unroll 8
      for (int kk = 0; kk < DD; ++kk) {
        unsigned u = WSu[h * 2048 + kk * 32 + cg2];
        float wx = bf_lo(u), wy = bf_hi(u);
#pragma unroll
        for (int i = 0; i < 4; ++i) {
          float x = MG[r0 + i][kk];
          a2[i][0] = fmaf(x, wx, a2[i][0]); a2[i][1] = fmaf(x, wy, a2[i][1]);
        }
      }
      float2 v2 = *(const float2*)(att_v + hh * DD + c0);
#pragma unroll
      for (int i = 0; i < 4; ++i) {
        float p = tanh_f(a2[i][0]) * v2.x + tanh_f(a2[i][1]) * v2.y;
        p = gredsum32(p);
        if (cg2 == 0) scS[hh][k][(strip & 3) * 4 + i] = p;
      }
    }
    __syncthreads();                 // WSu reads + scS writes done
    if (pr == 0) {
#pragma unroll
      for (int p = 0; p < 4; ++p)
        ((uint4*)WSu)[p * 256 + tid] = ((const uint4*)(wpack + ATTP + 4096))[p * 256 + tid];
      __syncthreads();
    }
  }
  // ---- stage wuP + hop-softmax mix -> X ----
#pragma unroll
  for (int p = 0; p < 4; ++p)
    ((uint4*)WSu)[p * 256 + tid] = ((const uint4*)(wpack + WUP))[p * 256 + tid];
  {
    int i = tid >> 4, d4 = tid & 15;    // 16 rows x 16 d4 = 256
    float W0 = 0.0f, W1 = 0.0f;
#pragma unroll
    for (int h = 0; h < NH; ++h) {
      float s0 = scS[h][0][i];
      float s1 = scS[h][1][i];
      float m = fmaxf(s0, s1);
      float e0 = __expf(s0 - m), e1 = __expf(s1 - m);
      float inv = 1.0f / (e0 + e1);
      W0 += e0 * inv; W1 += e1 * inv;
    }
    W0 *= 0.25f; W1 *= 0.25f;
    float4 ef = *(const float4*)(encIn + (size_t)(t0 + i) * DD + d4 * 4);
#pragma unroll
    for (int j = 0; j < 4; ++j) {
      int d = d4 * 4 + j;
      X[i][d] = W0 * MG[i][d] + W1 * MG[16 + i][d];
    }
    X[i][64 + d4 * 4]     = ef.x;
    X[i][64 + d4 * 4 + 1] = ef.y;
    X[i][64 + d4 * 4 + 2] = ef.z;
    X[i][64 + d4 * 4 + 3] = ef.w;
  }
  __syncthreads();
  // ---- GRU u-gate, full K=128 ----
  float au[2][2];
#pragma unroll
  for (int i = 0; i < 2; ++i) { au[i][0] = bu[c0]; au[i][1] = bu[c0 + 1]; }
#pragma unroll 8
  for (int kk = 0; kk < 2 * DD; ++kk) {
    unsigned u = WSu[kk * 32 + cg2];
    float wx = bf_lo(u), wy = bf_hi(u);
#pragma unroll
    for (int i = 0; i < 2; ++i) {
      float x = X[gr0 + i][kk];
      au[i][0] = fmaf(x, wx, au[i][0]); au[i][1] = fmaf(x, wy, au[i][1]);
    }
  }
  float uu[2][2], encv[2][2];
#pragma unroll
  for (int i = 0; i < 2; ++i) {
    uu[i][0] = sigmoid_f(au[i][0]); uu[i][1] = sigmoid_f(au[i][1]);
    encv[i][0] = X[gr0 + i][64 + c0]; encv[i][1] = X[gr0 + i][64 + c0 + 1];
  }
  __syncthreads();
  // ---- stage wrP; r-gate full K=128 ----
#pragma unroll
  for (int p = 0; p < 4; ++p)
    ((uint4*)WSu)[p * 256 + tid] = ((const uint4*)(wpack + WRP))[p * 256 + tid];
  __syncthreads();
  float ar[2][2];
#pragma unroll
  for (int i = 0; i < 2; ++i) { ar[i][0] = br[c0]; ar[i][1] = br[c0 + 1]; }
#pragma unroll 8
  for (int kk = 0; kk < 2 * DD; ++kk) {
    unsigned u = WSu[kk * 32 + cg2];
    float wx = bf_lo(u), wy = bf_hi(u);
#pragma unroll
    for (int i = 0; i < 2; ++i) {
      float x = X[gr0 + i][kk];
      ar[i][0] = fmaf(x, wx, ar[i][0]); ar[i][1] = fmaf(x, wy, ar[i][1]);
    }
  }
  __syncthreads();                   // all X enc-half reads done
  // ---- apply r-gate + stage wcP ----
#pragma unroll
  for (int i = 0; i < 2; ++i) {
    X[gr0 + i][64 + c0]     = encv[i][0] * sigmoid_f(ar[i][0]);
    X[gr0 + i][64 + c0 + 1] = encv[i][1] * sigmoid_f(ar[i][1]);
  }
#pragma unroll
  for (int p = 0; p < 4; ++p)
    ((uint4*)WSu)[p * 256 + tid] = ((const uint4*)(wpack + WCP))[p * 256 + tid];
  __syncthreads();
  // ---- c-gate full K=128 + combine -> encOut + EO (MG alias rows 0..15) ----
  float ac[2][2];
#pragma unroll
  for (int i = 0; i < 2; ++i) { ac[i][0] = bc[c0]; ac[i][1] = bc[c0 + 1]; }
#pragma unroll 8
  for (int kk = 0; kk < 2 * DD; ++kk) {
    unsigned u = WSu[kk * 32 + cg2];
    float wx = bf_lo(u), wy = bf_hi(u);
#pragma unroll
    for (int i = 0; i < 2; ++i) {
      float x = X[gr0 + i][kk];
      ac[i][0] = fmaf(x, wx, ac[i][0]); ac[i][1] = fmaf(x, wy, ac[i][1]);
    }
  }
#pragma unroll
  for (int i = 0; i < 2; ++i) {
    float e0 = uu[i][0] * encv[i][0] + (1.0f - uu[i][0]) * tanh_f(ac[i][0]);
    float e1 = uu[i][1] * encv[i][1] + (1.0f - uu[i][1]) * tanh_f(ac[i][1]);
    *(float2*)(encOut + (size_t)(t0 + gr0 + i) * DD + c0) = make_float2(e0, e1);
    MG[gr0 + i][c0] = e0; MG[gr0 + i][c0 + 1] = e1;
  }
  if (do_decode) {
    __syncthreads();                 // EO(MG) complete + WSu(wc) reads done
    // ---- stage dwP+uwP; decode both heads in one phase ----
#pragma unroll
    for (int p = 0; p < 4; ++p)
      ((uint4*)WSu)[p * 256 + tid] = ((const uint4*)(wpack + DECP))[p * 256 + tid];
    __syncthreads();
    float hd[2][2], hq[2][2];
#pragma unroll
    for (int i = 0; i < 2; ++i) {
      hd[i][0] = db0[c0]; hd[i][1] = db0[c0 + 1];
      hq[i][0] = ub0[c0]; hq[i][1] = ub0[c0 + 1];
    }
#pragma unroll 8
    for (int kk = 0; kk < DD; ++kk) {
      unsigned ud = WSu[kk * 32 + cg2];
      unsigned uq = WSu[2048 + kk * 32 + cg2];
      float dx = bf_lo(ud), dy = bf_hi(ud);
      float qx = bf_lo(uq), qy = bf_hi(uq);
#pragma unroll
      for (int i = 0; i < 2; ++i) {
        float x = MG[gr0 + i][kk];
        hd[i][0] = fmaf(x, dx, hd[i][0]); hd[i][1] = fmaf(x, dy, hd[i][1]);
        hq[i][0] = fmaf(x, qx, hq[i][0]); hq[i][1] = fmaf(x, qy, hq[i][1]);
      }
    }
    float2 dv = *(const float2*)(dw1 + c0);
    float2 qv = *(const float2*)(uw1 + c0);
#pragma unroll
    for (int i = 0; i < 2; ++i) {
      float p = hd[i][0] * dv.x + hd[i][1] * dv.y;
      float q = hq[i][0] * qv.x + hq[i][1] * qv.y;
      p = gredsum32(p);
      q = gredsum32(q);
      if (cg2 == 0) {
        pred[t0 + gr0 + i] = p + db1[0];
        dualp[t0 + gr0 + i] = q + ub1[0];
      }
    }
  }
}

// ------- fused: sparsemax (fixed-point tau) + CSC scatter + dual edge cost -------
__global__ void __launch_bounds__(256) k_primal_dual(
    const int* __restrict__ nb_cols, const int* __restrict__ nb_cnt,
    const float* __restrict__ pred, const float* __restrict__ dualp,
    const float* __restrict__ dem,
    float* __restrict__ rowsum,
    int* __restrict__ col_cnt, int* __restrict__ col_rows, float* __restrict__ col_vals,
    float* __restrict__ out) {
  __shared__ float bacc[BB];
  if (threadIdx.x < BB) bacc[threadIdx.x] = 0.0f;
  __syncthreads();
  int w = threadIdx.x >> 6, lane = threadIdx.x & 63;
  int row = blockIdx.x * 4 + w;
  int b = row / VV;
  int n = nb_cnt[row];
  int c = (lane < n) ? nb_cols[(size_t)row * CAP + lane] : 0;
  const float* predB = pred + (size_t)b * VV;
  const float* dualB = dualp + (size_t)b * VV;
  float z = (lane < n) ? predB[c] : -1e30f;
  float tau = 0.0f;
  if (n > 0) {
    bool in = (lane < n);
    for (int it = 0; it < 64; ++it) {
      float s = wredsum(in ? z : 0.0f);
      int cnt = (int)__popcll(__ballot(in));
      tau = (s - 1.0f) / (float)cnt;
      bool nin = (z > tau);
      if (__ballot(nin) == __ballot(in)) break;
      in = nin;
    }
  }
  float pv = (lane < n) ? fmaxf(z - tau, 0.0f) : 0.0f;
  float s2 = wredsum(pv * pv);
  if (lane == 0) rowsum[row] = s2;
  if (pv > 0.0f) {
    int g = b * VV + c;
    int j = atomicAdd(&col_cnt[g], 1);
    if (j < CAP) {
      col_rows[(size_t)g * CAP + j] = row - b * VV;
      col_vals[(size_t)g * CAP + j] = pv;
    }
  }
  float du = dualp[row];
  float es = 0.0f;
  if (lane < n) {
    float dd = du - dualB[c];
    float f = 0.0f, acm = 0.0f;
#pragma unroll
    for (int t = 0; t < 8; ++t) {
      float look = f - 0.9f * acm;
      float grad = 2.0f * look - dd;
      acm = 0.9f * acm + 0.1f * grad;
      f = fmaxf(f - acm, 0.0f);
    }
    es = f * f - dd * f;
  }
  float contrib = -es;
  if (lane == 0) contrib += du * dem[row];
  float ws_ = wredsum(contrib);
  if (lane == 0) atomicAdd(&bacc[b], ws_);
  __syncthreads();
  if (threadIdx.x < BB) {
    float t = bacc[threadIdx.x];
    if (t != 0.0f) atomicAdd(&out[threadIdx.x], t);
  }
}

// ------- fused flow iterations (per-graph block) + flow cost -------
__global__ void __launch_bounds__(1024) k_flow(
    const int* __restrict__ col_cnt, const int* __restrict__ col_rows,
    const float* __restrict__ col_vals, const float* __restrict__ dem,
    const float* __restrict__ rowsum, float* __restrict__ out) {
  __shared__ float aS[VV];
  __shared__ float red[16];
  int b = blockIdx.x;
  int tid = threadIdx.x;
  const float* demB = dem + (size_t)b * VV;
  for (int v = tid; v < VV; v += 1024) aS[v] = fmaxf(-demB[v], 0.0f);
  __syncthreads();
  for (int t = 0; t < 7; ++t) {
    float nv0 = 0.0f, nv1 = 0.0f;
    {
      int v = tid;
      if (v < VV) {
        int g = b * VV + v;
        int n = col_cnt[g]; if (n > CAP) n = CAP;
        const int* cr = col_rows + (size_t)g * CAP;
        const float* cv = col_vals + (size_t)g * CAP;
        float acc = 0.0f;
        for (int j = 0; j < n; ++j) acc += cv[j] * aS[cr[j]];
        nv0 = fmaxf(acc - demB[v], 0.0f);
      }
      v = tid + 1024;
      if (v < VV) {
        int g = b * VV + v;
        int n = col_cnt[g]; if (n > CAP) n = CAP;
        const int* cr = col_rows + (size_t)g * CAP;
        const float* cv = col_vals + (size_t)g * CAP;
        float acc = 0.0f;
        for (int j = 0; j < n; ++j) acc += cv[j] * aS[cr[j]];
        nv1 = fmaxf(acc - demB[v], 0.0f);
      }
    }
    __syncthreads();
    if (tid < VV) aS[tid] = nv0;
    if (tid + 1024 < VV) aS[tid + 1024] = nv1;
    __syncthreads();
  }
  float fc = 0.0f;
  for (int v = tid; v < VV; v += 1024) { float a = aS[v]; fc += a * a * rowsum[b * VV + v]; }
  fc = wredsum(fc);
  int wid = tid >> 6, lane = tid & 63;
  if (lane == 0) red[wid] = fc;
  __syncthreads();
  if (tid == 0) {
    float s = 0.0f;
#pragma unroll
    for (int i = 0; i < 16; ++i) s += red[i];
    atomicAdd(&out[b], s);
  }
}

extern "C" void kernel_launch(void* const* d_in, const int* in_sizes, int n_in,
                              void* d_out, int out_size, void* d_ws, size_t ws_size,
                              hipStream_t stream) {
  const float* feat   = (const float*)d_in[0];
  const float* emb    = (const float*)d_in[1];
  const float* dem    = (const float*)d_in[2];
  const float* nb     = (const float*)d_in[4];   // [K,B,V,V]
  const float* enc_w0 = (const float*)d_in[5];
  const float* enc_b0 = (const float*)d_in[6];
  const float* enc_w1 = (const float*)d_in[7];
  const float* enc_b1 = (const float*)d_in[8];
  const float* agg_w  = (const float*)d_in[9];
  const float* agg_b  = (const float*)d_in[10];
  const float* att_w  = (const float*)d_in[11];
  const float* att_b  = (const float*)d_in[12];
  const float* att_v  = (const float*)d_in[13];
  const float* gru_wu = (const float*)d_in[14];
  const float* gru_bu = (const float*)d_in[15];
  const float* gru_wr = (const float*)d_in[16];
  const float* gru_br = (const float*)d_in[17];
  const float* gru_wc = (const float*)d_in[18];
  const float* gru_bc = (const float*)d_in[19];
  const float* dec_w0 = (const float*)d_in[20];
  const float* dec_b0 = (const float*)d_in[21];
  const float* dec_w1 = (const float*)d_in[22];
  const float* dec_b1 = (const float*)d_in[23];
  const float* dual_w0= (const float*)d_in[24];
  const float* dual_b0= (const float*)d_in[25];
  const float* dual_w1= (const float*)d_in[26];
  const float* dual_b1= (const float*)d_in[27];
  float* out = (float*)d_out;

  float* enc0 = (float*)d_ws;                            // NROW*DD f32
  float* enc1 = enc0 + (size_t)NROW * DD;
  float* msg      = enc1 + (size_t)NROW * DD;            // NKROW*DD
  float* pred     = msg + (size_t)NKROW * DD;
  float* dualp    = pred + NROW;
  float* rowsum   = dualp + NROW;
  float* col_vals = rowsum + NROW;                       // NROW*CAP
  int* col_cnt  = (int*)(col_vals + (size_t)NROW * CAP);
  int* nb_cnt   = col_cnt + NROW;                        // NKROW
  int* col_rows = nb_cnt + NKROW;                        // NROW*CAP
  int* nb_cols  = col_rows + (size_t)NROW * CAP;         // NROW*CAP + NROW*NB2CAP
  unsigned* wpack = (unsigned*)(nb_cols + (size_t)NROW * CAP + (size_t)NROW * NB2CAP);

  (void)in_sizes; (void)n_in; (void)ws_size;

  k_pre<<<ENC2B + CSR2B + 1, 512, 0, stream>>>(
      nb, nb_cols, nb_cnt, emb, feat, enc_w0, enc_b0, enc_w1, enc_b1, enc0,
      agg_w, att_w, gru_wu, gru_wr, gru_wc, dec_w0, dual_w0, wpack,
      col_cnt, out, out_size);

  const float* encIn = enc0;
  float* encOut = enc1;
  for (int l = 0; l < 2; ++l) {
    k_gather<<<NKROW / 4, 256, 0, stream>>>(nb_cols, nb_cnt, encIn, msg);
    k_layer<<<NROW / 16, 256, 0, stream>>>(msg, encIn, wpack,
                                           agg_b, att_b, att_v,
                                           gru_bu, gru_br, gru_bc,
                                           encOut,
                                           (l == 1) ? 1 : 0,
                                           dec_b0, dec_w1, dec_b1,
                                           dual_b0, dual_w1, dual_b1, pred, dualp);
    const float* t = encIn; encIn = encOut; encOut = (float*)t;
  }

  k_primal_dual<<<NROW / 4, 256, 0, stream>>>(nb_cols, nb_cnt, pred, dualp, dem,
                                              rowsum, col_cnt, col_rows, col_vals, out);
  k_flow<<<BB, 1024, 0, stream>>>(col_cnt, col_rows, col_vals, dem, rowsum, out);
}